// Round 2
// baseline (253.922 us; speedup 1.0000x reference)
//
#include <hip/hip_runtime.h>

#define FEAT_H 32
#define FEAT_W 110
#define NCELL (FEAT_H * FEAT_W) /* 3520 */
#define STRIDEPX 16
#define NB 8
#define NG 32
#define NANC 36
#define NC 4
#define A_TOTAL (NCELL * NANC) /* 126720 */

#define SLICES 4                /* colpass cell-slices per column */
#define CPB 512                 /* colpass threads/block */
#define CSLICE (NCELL / SLICES) /* 880 cells per slice */

#define BLK 512              /* k_main: 512 blocks x 512 thr = 2 blocks/CU = 16 waves/CU */
#define CHK 512              /* anchors per chunk (= BLK) */
#define NCHK 248             /* ceil(A_TOTAL/CHK); last chunk partial */
#define G2 512
#define CB (G2 / NB)         /* 64 chunk stride per image */
#define MAXSLOTS 4           /* ceil(NCHK/CB) */

__device__ __forceinline__ float smooth_l1(float x) {
    float ax = fabsf(x);
    return ax < 1.f ? 0.5f * ax * ax : ax - 0.5f;
}

// ws: colpart[256*SLICES] u64 @0 (8 KB), acc[8] f32 @8192, done u32 @8224.

// Column-max pass, sliced: 4 blocks per (b,g) column, each covering 880 cells.
// 1024 blocks x 512 thr = 32 waves/CU (vs 16 before). Inner argmax tracks a
// (float,int) pair (3 ops) instead of a packed u64 (7 ops); the u64 packing
// (iou<<32 | ~a) happens once per block, so the downstream merge keeps the
// exact first-occurrence tie rule (max iou, then smallest a).
__global__ __launch_bounds__(CPB, 8) void k_colpass(
    const float* __restrict__ gt_boxes, const int* __restrict__ gt_valid,
    const float* __restrict__ anchors, unsigned long long* __restrict__ colpart,
    float* __restrict__ acc, unsigned* __restrict__ done) {
#pragma clang fp contract(off)
    __shared__ float4 anch4[NANC];
    __shared__ float aarea[NANC];
    __shared__ float wbf[CPB / 64];
    __shared__ int wbi[CPB / 64];
    const int tid = threadIdx.x;
    const int bg = blockIdx.x >> 2; // column (b*NG+g), 0..255
    const int sl = blockIdx.x & 3;  // cell slice, 0..3
    if (blockIdx.x == 0) { // ws is 0xAA-poisoned each call
        if (tid < 8) acc[tid] = 0.f;
        if (tid == 8) *done = 0u;
    }
    if (tid < NANC) {
        const float* ap = anchors + tid * 9;
        const float4 v = make_float4(ap[0], ap[1], ap[2], ap[3]);
        anch4[tid] = v;
        aarea[tid] = (v.z - v.x + 1.f) * (v.w - v.y + 1.f);
    }
    __syncthreads();
    float bf = -1.f;
    int bi = 0;
    if (gt_valid[bg]) {
        const float g0 = gt_boxes[bg * 4 + 0], g1 = gt_boxes[bg * 4 + 1];
        const float g2 = gt_boxes[bg * 4 + 2], g3 = gt_boxes[bg * 4 + 3];
        const float ag = (g2 - g0 + 1.f) * (g3 - g1 + 1.f);
        for (int c = sl * CSLICE + tid; c < (sl + 1) * CSLICE; c += CPB) {
            const float sx = (float)((c % FEAT_W) * STRIDEPX);
            const float sy = (float)((c / FEAT_W) * STRIDEPX);
            int a = c * NANC;
#pragma unroll 4
            for (int t = 0; t < NANC; ++t, ++a) {
                const float4 av = anch4[t];          // wave-uniform broadcast
                const float r0 = sx + av.x, r1 = sy + av.y;
                const float r2 = sx + av.z, r3 = sy + av.w;
                const float xx1 = fmaxf(r0, g0), yy1 = fmaxf(r1, g1);
                const float xx2 = fminf(r2, g2), yy2 = fminf(r3, g3);
                const float iw = fmaxf(xx2 - xx1 + 1.f, 0.f);
                const float ih = fmaxf(yy2 - yy1 + 1.f, 0.f);
                const float inter = iw * ih;
                const float iou =
                    inter * __builtin_amdgcn_rcpf(aarea[t] + ag - inter);
                if (iou > bf) { bf = iou; bi = a; } // strict '>': first occurrence
            }
        }
    }
    for (int off = 32; off; off >>= 1) {
        const float of = __shfl_down(bf, off, 64);
        const int oi = __shfl_down(bi, off, 64);
        if (of > bf || (of == bf && oi < bi)) { bf = of; bi = oi; }
    }
    if ((tid & 63) == 0) { wbf[tid >> 6] = bf; wbi[tid >> 6] = bi; }
    __syncthreads();
    if (tid == 0) {
        for (int w = 1; w < CPB / 64; ++w)
            if (wbf[w] > bf || (wbf[w] == bf && wbi[w] < bi)) {
                bf = wbf[w]; bi = wbi[w];
            }
        const unsigned long long p = (bf < 0.f) ? 0ull :
            (((unsigned long long)__float_as_uint(bf) << 32) |
             (unsigned long long)(0xFFFFFFFFu - (unsigned)bi));
        colpart[bg * SLICES + sl] = p;
    }
}

// Row pass + loss. 512 blocks x 512 threads (2 blocks/CU -> serial prologue of
// one block overlaps the other's compute), b = blk/CB, chunks c0 + k*CB (<=4).
// cls pipelined two chunks ahead. CHK=512 leaves a partial tail chunk ->
// 'live' guard on the last chunk's upper lanes.
__global__ __launch_bounds__(BLK, 4) void k_main(
    const float* __restrict__ cls, const float* __restrict__ bbox_2d,
    const float* __restrict__ bbox_3d, const float* __restrict__ gt_boxes,
    const float* __restrict__ gt_3d, const int* __restrict__ gt_labels,
    const int* __restrict__ gt_valid, const float* __restrict__ anchors,
    const float* __restrict__ means, const float* __restrict__ stds,
    const unsigned long long* __restrict__ colpart, float* __restrict__ acc,
    unsigned* __restrict__ done, float* __restrict__ out) {
#pragma clang fp contract(off)
    __shared__ float ax0_s[NANC], ay0_s[NANC], ax1_s[NANC], ay1_s[NANC];
    __shared__ float anch9[NANC * 9];
    __shared__ float4 gtb4_s[NG];
    __shared__ float ags_s[NG];
    __shared__ float gt3_s[NG * 7];
    __shared__ int lbl_s[NG];
    __shared__ int bag_s[NG], forceg_s[NG];
    __shared__ float mean_s[11], rstd_s[11];
    __shared__ unsigned vmask_s;
    __shared__ float red[5][BLK / 64];
    __shared__ int fixmap[MAXSLOTS * BLK]; // 8 KB

    const int tid = threadIdx.x;
    const int b = blockIdx.x / CB;
    const int c0 = blockIdx.x % CB;

    // ---- staging ----
    for (int i = tid; i < NANC * 9; i += BLK) anch9[i] = anchors[i];
    if (tid < NANC) {
        const float* ap = anchors + tid * 9;
        ax0_s[tid] = ap[0]; ay0_s[tid] = ap[1];
        ax1_s[tid] = ap[2]; ay1_s[tid] = ap[3];
    }
    for (int i = tid; i < NG * 7; i += BLK) gt3_s[i] = gt_3d[b * NG * 7 + i];
    int myval = 0;
    if (tid < NG) {
        const float4 q = ((const float4*)gt_boxes)[b * NG + tid];
        gtb4_s[tid] = q;
        ags_s[tid] = (q.z - q.x + 1.f) * (q.w - q.y + 1.f);
        lbl_s[tid] = gt_labels[b * NG + tid];
        myval = gt_valid[b * NG + tid];
        // merge the 4 column slices; packed-max preserves the exact
        // (max iou, then smallest a) first-occurrence rule
        const unsigned long long* cpp = colpart + (b * NG + tid) * SLICES;
        unsigned long long p = cpp[0];
        if (cpp[1] > p) p = cpp[1];
        if (cpp[2] > p) p = cpp[2];
        if (cpp[3] > p) p = cpp[3];
        const float gbest = __uint_as_float((unsigned)(p >> 32));
        bag_s[tid] = myval ? (int)(0xFFFFFFFFu - (unsigned)(p & 0xFFFFFFFFull)) : 0;
        forceg_s[tid] = (myval && gbest >= 0.35f) ? 1 : 0;
    }
    unsigned long long bal = __ballot(tid < NG && myval);
    if (tid == 0) vmask_s = (unsigned)bal;
    if (tid < 11) { mean_s[tid] = means[tid]; rstd_s[tid] = 1.0f / stds[tid]; }
    const int nslots = (NCHK - 1 - c0) / CB + 1; // 4 or 3
    for (int i = tid; i < nslots * BLK; i += BLK) fixmap[i] = -1;
    __syncthreads();
    if (tid == 0) {
        // ascending-g serial build: last-update-wins for agt, OR for force
        // (exact jax .at[ba].set / .at[ba].max gather-before-scatter)
        for (int g = 0; g < NG; ++g) {
            const int ba = bag_s[g];
            const int cb = ba >> 9; // chunk index (CHK=512)
            if (cb % CB == c0) {
                const int k = (cb - c0) / CB;
                const int idx = k * BLK + (ba & (CHK - 1));
                const int e = fixmap[idx];
                const int anyf = ((e >= 0) ? (e & 0x40000000) : 0) |
                                 (forceg_s[g] ? 0x40000000 : 0);
                const int code = forceg_s[g] ? g : 32; // 32 = keep agt_orig
                fixmap[idx] = anyf | code;
            }
        }
    }
    __syncthreads();
    const unsigned vmask = vmask_s;

    // ---- main loop (cls pipelined TWO chunks ahead) ----
    float sum_ce = 0.f, sum_act = 0.f, sum_fg = 0.f, sum_2d = 0.f, sum_3d = 0.f;
    const size_t bbase = (size_t)b * A_TOTAL;

    int chunk = c0;
    int a0i = chunk * CHK + tid;
    int ae = a0i < A_TOTAL ? a0i : (A_TOTAL - 1);
    float4 cv0 = *(const float4*)(cls + (bbase + ae) * NC);
    float4 cv1 = make_float4(0.f, 0.f, 0.f, 0.f);
    if (nslots > 1) {
        int a1i = (chunk + CB) * CHK + tid;
        int ae1 = a1i < A_TOTAL ? a1i : (A_TOTAL - 1);
        cv1 = *(const float4*)(cls + (bbase + ae1) * NC);
    }

    for (int k = 0; k < nslots; ++k) {
        float4 cv2 = make_float4(0.f, 0.f, 0.f, 0.f);
        if (k + 2 < nslots) {
            int a2i = (chunk + 2 * CB) * CHK + tid;
            int ae2 = a2i < A_TOTAL ? a2i : (A_TOTAL - 1);
            cv2 = *(const float4*)(cls + (bbase + ae2) * NC);
        }

        const int araw = chunk * CHK + tid;
        const bool live = araw < A_TOTAL;
        const int a = live ? araw : (A_TOTAL - 1); // clamped for safe math
        const int t = a % NANC;
        const int cell = a / NANC;
        const float sx = (float)((cell % FEAT_W) * STRIDEPX);
        const float sy = (float)((cell / FEAT_W) * STRIDEPX);
        const float r0 = sx + ax0_s[t], r1 = sy + ay0_s[t];
        const float r2 = sx + ax1_s[t], r3 = sy + ay1_s[t];
        const float ar = (r2 - r0 + 1.f) * (r3 - r1 + 1.f);

        // grouped argmax: 4 groups of 8, scalar regs; strict '>' ascending
        // preserves first-occurrence exactly (incl. all-invalid -> 0)
        float m0 = -1.f, m1 = -1.f, m2 = -1.f, m3 = -1.f;
        int i0 = 0, i1 = 8, i2 = 16, i3 = 24;
#pragma unroll
        for (int g = 0; g < NG; ++g) {
            const float4 q = gtb4_s[g];              // wave-uniform broadcast
            const float xx1 = fmaxf(r0, q.x), yy1 = fmaxf(r1, q.y);
            const float xx2 = fminf(r2, q.z), yy2 = fminf(r3, q.w);
            const float iw = fmaxf(xx2 - xx1 + 1.f, 0.f);
            const float ih = fmaxf(yy2 - yy1 + 1.f, 0.f);
            const float inter = iw * ih;
            float iou = inter * __builtin_amdgcn_rcpf(ar + ags_s[g] - inter);
            iou = ((vmask >> g) & 1u) ? iou : -1.0f;
            if (g < 8)       { if (iou > m0) { m0 = iou; i0 = g; } }
            else if (g < 16) { if (iou > m1) { m1 = iou; i1 = g; } }
            else if (g < 24) { if (iou > m2) { m2 = iou; i2 = g; } }
            else             { if (iou > m3) { m3 = iou; i3 = g; } }
        }
        float best = m0; int agt = i0;
        if (m1 > best) { best = m1; agt = i1; }
        if (m2 > best) { best = m2; agt = i2; }
        if (m3 > best) { best = m3; agt = i3; }

        bool fg = best >= 0.5f;
        const int agt_orig = agt;
        const int f = fixmap[k * BLK + tid];
        if (f >= 0) {
            if (f & 0x40000000) fg = true;
            const int code = f & 63;
            agt = (code == 32) ? agt_orig : code;
        }
        if (!live) fg = false; // tail lanes contribute nothing
        const bool bgm = live && (!fg) && (best < 0.5f) && (best >= 0.0f);
        const float active = (fg || bgm) ? 1.f : 0.f;
        const int lbl = fg ? lbl_s[agt] : 0;

        const float mx = fmaxf(fmaxf(cv0.x, cv0.y), fmaxf(cv0.z, cv0.w));
        const float se = __expf(cv0.x - mx) + __expf(cv0.y - mx) +
                         __expf(cv0.z - mx) + __expf(cv0.w - mx);
        const float lse = mx + __logf(se);
        const float csel = (lbl == 0) ? cv0.x : (lbl == 1) ? cv0.y
                         : (lbl == 2) ? cv0.z : cv0.w;
        sum_ce += (lse - csel) * active;
        sum_act += active;

        if (fg) { // rare: exec-masked gathers, issued only when needed
            sum_fg += 1.f;
            const float w = r2 - r0 + 1.f, h = r3 - r1 + 1.f;
            const float rw = __builtin_amdgcn_rcpf(w);
            const float rh = __builtin_amdgcn_rcpf(h);
            const float cx = r0 + 0.5f * w, cy = r1 + 0.5f * h;
            const float4 Gq = gtb4_s[agt];
            const float gw = Gq.z - Gq.x + 1.f, gh = Gq.w - Gq.y + 1.f;
            const float gcx = Gq.x + 0.5f * gw, gcy = Gq.y + 0.5f * gh;
            float t2[4];
            t2[0] = (gcx - cx) * rw;
            t2[1] = (gcy - cy) * rh;
            t2[2] = __logf(gw * rw);
            t2[3] = __logf(gh * rh);
            const float4 b2 = *(const float4*)(bbox_2d + (bbase + a) * 4);
            const float b2v[4] = {b2.x, b2.y, b2.z, b2.w};
            float l2 = 0.f;
            for (int j = 0; j < 4; ++j)
                l2 += smooth_l1(b2v[j] - (t2[j] - mean_s[j]) * rstd_s[j]);
            sum_2d += l2;
            const float* q3p = &gt3_s[agt * 7];
            const float* b3 = bbox_3d + (bbase + a) * 7;
            float t3[7];
            t3[0] = (q3p[0] - cx) * rw;
            t3[1] = (q3p[1] - cy) * rh;
            t3[2] = q3p[2] - anch9[t * 9 + 4];
            t3[3] = __logf(q3p[3] * __builtin_amdgcn_rcpf(anch9[t * 9 + 5]));
            t3[4] = __logf(q3p[4] * __builtin_amdgcn_rcpf(anch9[t * 9 + 6]));
            t3[5] = __logf(q3p[5] * __builtin_amdgcn_rcpf(anch9[t * 9 + 7]));
            t3[6] = q3p[6] - anch9[t * 9 + 8];
            float l3 = 0.f;
            for (int j = 0; j < 7; ++j)
                l3 += smooth_l1(b3[j] - (t3[j] - mean_s[4 + j]) * rstd_s[4 + j]);
            sum_3d += l3;
        }
        cv0 = cv1;
        cv1 = cv2;
        chunk += CB;
    }

    // ---- block reduce -> 5 atomics; last block finishes ----
    float vals[5] = {sum_ce, sum_act, sum_fg, sum_2d, sum_3d};
#pragma unroll
    for (int j = 0; j < 5; ++j) {
        float v = vals[j];
        for (int off = 32; off; off >>= 1) v += __shfl_down(v, off, 64);
        if ((tid & 63) == 0) red[j][tid >> 6] = v;
    }
    __syncthreads();
    if (tid == 0) {
        for (int j = 0; j < 5; ++j) {
            float s = 0.f;
            for (int w = 0; w < BLK / 64; ++w) s += red[j][w];
            atomicAdd(&acc[j], s);
        }
        __threadfence();
        const unsigned old = atomicAdd(done, 1u);
        if (old == G2 - 1) {
            const float a0 = atomicAdd(&acc[0], 0.f);
            const float a1 = atomicAdd(&acc[1], 0.f);
            const float a2 = atomicAdd(&acc[2], 0.f);
            const float a3 = atomicAdd(&acc[3], 0.f);
            const float a4 = atomicAdd(&acc[4], 0.f);
            const float nact = fmaxf(a1, 1.f);
            const float nfg = fmaxf(a2, 1.f);
            out[0] = a0 / nact + a3 / nfg + a4 / nfg;
        }
    }
}

extern "C" void kernel_launch(void* const* d_in, const int* in_sizes, int n_in,
                              void* d_out, int out_size, void* d_ws, size_t ws_size,
                              hipStream_t stream) {
    const float* cls      = (const float*)d_in[0];
    const float* bbox_2d  = (const float*)d_in[1];
    const float* bbox_3d  = (const float*)d_in[2];
    const float* gt_boxes = (const float*)d_in[3];
    const float* gt_3d    = (const float*)d_in[4];
    const int*   gt_labels= (const int*)d_in[5];
    const int*   gt_valid = (const int*)d_in[6];
    const float* anchors  = (const float*)d_in[7];
    const float* means    = (const float*)d_in[8];
    const float* stds     = (const float*)d_in[9];

    unsigned long long* colpart = (unsigned long long*)d_ws;  // 8 KB @0
    float* acc = (float*)((char*)d_ws + 8192);
    unsigned* done = (unsigned*)((char*)d_ws + 8192 + 32);
    float* out = (float*)d_out;

    k_colpass<<<NB * NG * SLICES, CPB, 0, stream>>>(gt_boxes, gt_valid, anchors,
                                                    colpart, acc, done);
    k_main<<<G2, BLK, 0, stream>>>(cls, bbox_2d, bbox_3d, gt_boxes, gt_3d,
                                   gt_labels, gt_valid, anchors, means, stds,
                                   colpart, acc, done, out);
}

// Round 3
// 182.664 us; speedup vs baseline: 1.3901x; 1.3901x over previous
//
#include <hip/hip_runtime.h>

#define FEAT_H 32
#define FEAT_W 110
#define NCELL (FEAT_H * FEAT_W) /* 3520 */
#define STRIDEPX 16
#define NB 8
#define NG 32
#define NANC 36
#define NC 4
#define A_TOTAL (NCELL * NANC) /* 126720 */

#define SLICES 4                /* colpass cell-slices per column */
#define CPB 512                 /* colpass threads/block */
#define CSLICE (NCELL / SLICES) /* 880 cells per slice */

#define BLK 512              /* k_main: 512 blocks x 512 thr = 2 blocks/CU = 16 waves/CU */
#define CHK 512              /* anchors per chunk (= BLK) */
#define NCHK 248             /* ceil(A_TOTAL/CHK); last chunk partial */
#define G2 512
#define CB (G2 / NB)         /* 64 chunk stride per image */
#define MAXSLOTS 4           /* ceil(NCHK/CB) */

__device__ __forceinline__ float smooth_l1(float x) {
    float ax = fabsf(x);
    return ax < 1.f ? 0.5f * ax * ax : ax - 0.5f;
}

// ws: colpart[256*SLICES] u64 @0 (8 KB), acc[8] f32 @8192, done u32 @8224.

// NOTE (round-2 post-mortem): do NOT pass a min-waves arg to __launch_bounds__
// here — (512,4) halved the VGPR budget to 64 and spilled ~168 MB/dispatch to
// scratch (WRITE_SIZE 2.6->168830 KB). Grid sizing alone (512 blocks = 2/CU)
// delivers the occupancy; the allocator needs its full 128 VGPR.

// Column-max pass, sliced: 4 blocks per (b,g) column, each covering 880 cells.
// 1024 blocks x 512 thr. Inner argmax tracks a (float,int) pair (3 ops)
// instead of a packed u64 (7 ops); the u64 packing (iou<<32 | ~a) happens
// once per block, so the downstream merge keeps the exact first-occurrence
// tie rule (max iou, then smallest a).
__global__ __launch_bounds__(CPB) void k_colpass(
    const float* __restrict__ gt_boxes, const int* __restrict__ gt_valid,
    const float* __restrict__ anchors, unsigned long long* __restrict__ colpart,
    float* __restrict__ acc, unsigned* __restrict__ done) {
#pragma clang fp contract(off)
    __shared__ float4 anch4[NANC];
    __shared__ float aarea[NANC];
    __shared__ float wbf[CPB / 64];
    __shared__ int wbi[CPB / 64];
    const int tid = threadIdx.x;
    const int bg = blockIdx.x >> 2; // column (b*NG+g), 0..255
    const int sl = blockIdx.x & 3;  // cell slice, 0..3
    if (blockIdx.x == 0) { // ws is 0xAA-poisoned each call
        if (tid < 8) acc[tid] = 0.f;
        if (tid == 8) *done = 0u;
    }
    if (tid < NANC) {
        const float* ap = anchors + tid * 9;
        const float4 v = make_float4(ap[0], ap[1], ap[2], ap[3]);
        anch4[tid] = v;
        aarea[tid] = (v.z - v.x + 1.f) * (v.w - v.y + 1.f);
    }
    __syncthreads();
    float bf = -1.f;
    int bi = 0;
    if (gt_valid[bg]) {
        const float g0 = gt_boxes[bg * 4 + 0], g1 = gt_boxes[bg * 4 + 1];
        const float g2 = gt_boxes[bg * 4 + 2], g3 = gt_boxes[bg * 4 + 3];
        const float ag = (g2 - g0 + 1.f) * (g3 - g1 + 1.f);
        for (int c = sl * CSLICE + tid; c < (sl + 1) * CSLICE; c += CPB) {
            const float sx = (float)((c % FEAT_W) * STRIDEPX);
            const float sy = (float)((c / FEAT_W) * STRIDEPX);
            int a = c * NANC;
#pragma unroll 4
            for (int t = 0; t < NANC; ++t, ++a) {
                const float4 av = anch4[t];          // wave-uniform broadcast
                const float r0 = sx + av.x, r1 = sy + av.y;
                const float r2 = sx + av.z, r3 = sy + av.w;
                const float xx1 = fmaxf(r0, g0), yy1 = fmaxf(r1, g1);
                const float xx2 = fminf(r2, g2), yy2 = fminf(r3, g3);
                const float iw = fmaxf(xx2 - xx1 + 1.f, 0.f);
                const float ih = fmaxf(yy2 - yy1 + 1.f, 0.f);
                const float inter = iw * ih;
                const float iou =
                    inter * __builtin_amdgcn_rcpf(aarea[t] + ag - inter);
                if (iou > bf) { bf = iou; bi = a; } // strict '>': first occurrence
            }
        }
    }
    for (int off = 32; off; off >>= 1) {
        const float of = __shfl_down(bf, off, 64);
        const int oi = __shfl_down(bi, off, 64);
        if (of > bf || (of == bf && oi < bi)) { bf = of; bi = oi; }
    }
    if ((tid & 63) == 0) { wbf[tid >> 6] = bf; wbi[tid >> 6] = bi; }
    __syncthreads();
    if (tid == 0) {
        for (int w = 1; w < CPB / 64; ++w)
            if (wbf[w] > bf || (wbf[w] == bf && wbi[w] < bi)) {
                bf = wbf[w]; bi = wbi[w];
            }
        const unsigned long long p = (bf < 0.f) ? 0ull :
            (((unsigned long long)__float_as_uint(bf) << 32) |
             (unsigned long long)(0xFFFFFFFFu - (unsigned)bi));
        colpart[bg * SLICES + sl] = p;
    }
}

// Row pass + loss. 512 blocks x 512 threads (2 blocks/CU -> serial prologue of
// one block overlaps the other's compute), b = blk/CB, chunks c0 + k*CB (<=4).
// cls pipelined two chunks ahead. CHK=512 leaves a partial tail chunk ->
// 'live' guard on the last chunk's upper lanes.
__global__ __launch_bounds__(BLK) void k_main(
    const float* __restrict__ cls, const float* __restrict__ bbox_2d,
    const float* __restrict__ bbox_3d, const float* __restrict__ gt_boxes,
    const float* __restrict__ gt_3d, const int* __restrict__ gt_labels,
    const int* __restrict__ gt_valid, const float* __restrict__ anchors,
    const float* __restrict__ means, const float* __restrict__ stds,
    const unsigned long long* __restrict__ colpart, float* __restrict__ acc,
    unsigned* __restrict__ done, float* __restrict__ out) {
#pragma clang fp contract(off)
    __shared__ float ax0_s[NANC], ay0_s[NANC], ax1_s[NANC], ay1_s[NANC];
    __shared__ float anch9[NANC * 9];
    __shared__ float4 gtb4_s[NG];
    __shared__ float ags_s[NG];
    __shared__ float gt3_s[NG * 7];
    __shared__ int lbl_s[NG];
    __shared__ int bag_s[NG], forceg_s[NG];
    __shared__ float mean_s[11], rstd_s[11];
    __shared__ unsigned vmask_s;
    __shared__ float red[5][BLK / 64];
    __shared__ int fixmap[MAXSLOTS * BLK]; // 8 KB

    const int tid = threadIdx.x;
    const int b = blockIdx.x / CB;
    const int c0 = blockIdx.x % CB;

    // ---- staging ----
    for (int i = tid; i < NANC * 9; i += BLK) anch9[i] = anchors[i];
    if (tid < NANC) {
        const float* ap = anchors + tid * 9;
        ax0_s[tid] = ap[0]; ay0_s[tid] = ap[1];
        ax1_s[tid] = ap[2]; ay1_s[tid] = ap[3];
    }
    for (int i = tid; i < NG * 7; i += BLK) gt3_s[i] = gt_3d[b * NG * 7 + i];
    int myval = 0;
    if (tid < NG) {
        const float4 q = ((const float4*)gt_boxes)[b * NG + tid];
        gtb4_s[tid] = q;
        ags_s[tid] = (q.z - q.x + 1.f) * (q.w - q.y + 1.f);
        lbl_s[tid] = gt_labels[b * NG + tid];
        myval = gt_valid[b * NG + tid];
        // merge the 4 column slices; packed-max preserves the exact
        // (max iou, then smallest a) first-occurrence rule
        const unsigned long long* cpp = colpart + (b * NG + tid) * SLICES;
        unsigned long long p = cpp[0];
        if (cpp[1] > p) p = cpp[1];
        if (cpp[2] > p) p = cpp[2];
        if (cpp[3] > p) p = cpp[3];
        const float gbest = __uint_as_float((unsigned)(p >> 32));
        bag_s[tid] = myval ? (int)(0xFFFFFFFFu - (unsigned)(p & 0xFFFFFFFFull)) : 0;
        forceg_s[tid] = (myval && gbest >= 0.35f) ? 1 : 0;
    }
    unsigned long long bal = __ballot(tid < NG && myval);
    if (tid == 0) vmask_s = (unsigned)bal;
    if (tid < 11) { mean_s[tid] = means[tid]; rstd_s[tid] = 1.0f / stds[tid]; }
    const int nslots = (NCHK - 1 - c0) / CB + 1; // 4 or 3
    for (int i = tid; i < nslots * BLK; i += BLK) fixmap[i] = -1;
    __syncthreads();
    if (tid == 0) {
        // ascending-g serial build: last-update-wins for agt, OR for force
        // (exact jax .at[ba].set / .at[ba].max gather-before-scatter)
        for (int g = 0; g < NG; ++g) {
            const int ba = bag_s[g];
            const int cb = ba >> 9; // chunk index (CHK=512)
            if (cb % CB == c0) {
                const int k = (cb - c0) / CB;
                const int idx = k * BLK + (ba & (CHK - 1));
                const int e = fixmap[idx];
                const int anyf = ((e >= 0) ? (e & 0x40000000) : 0) |
                                 (forceg_s[g] ? 0x40000000 : 0);
                const int code = forceg_s[g] ? g : 32; // 32 = keep agt_orig
                fixmap[idx] = anyf | code;
            }
        }
    }
    __syncthreads();
    const unsigned vmask = vmask_s;

    // ---- main loop (cls pipelined TWO chunks ahead) ----
    float sum_ce = 0.f, sum_act = 0.f, sum_fg = 0.f, sum_2d = 0.f, sum_3d = 0.f;
    const size_t bbase = (size_t)b * A_TOTAL;

    int chunk = c0;
    int a0i = chunk * CHK + tid;
    int ae = a0i < A_TOTAL ? a0i : (A_TOTAL - 1);
    float4 cv0 = *(const float4*)(cls + (bbase + ae) * NC);
    float4 cv1 = make_float4(0.f, 0.f, 0.f, 0.f);
    if (nslots > 1) {
        int a1i = (chunk + CB) * CHK + tid;
        int ae1 = a1i < A_TOTAL ? a1i : (A_TOTAL - 1);
        cv1 = *(const float4*)(cls + (bbase + ae1) * NC);
    }

    for (int k = 0; k < nslots; ++k) {
        float4 cv2 = make_float4(0.f, 0.f, 0.f, 0.f);
        if (k + 2 < nslots) {
            int a2i = (chunk + 2 * CB) * CHK + tid;
            int ae2 = a2i < A_TOTAL ? a2i : (A_TOTAL - 1);
            cv2 = *(const float4*)(cls + (bbase + ae2) * NC);
        }

        const int araw = chunk * CHK + tid;
        const bool live = araw < A_TOTAL;
        const int a = live ? araw : (A_TOTAL - 1); // clamped for safe math
        const int t = a % NANC;
        const int cell = a / NANC;
        const float sx = (float)((cell % FEAT_W) * STRIDEPX);
        const float sy = (float)((cell / FEAT_W) * STRIDEPX);
        const float r0 = sx + ax0_s[t], r1 = sy + ay0_s[t];
        const float r2 = sx + ax1_s[t], r3 = sy + ay1_s[t];
        const float ar = (r2 - r0 + 1.f) * (r3 - r1 + 1.f);

        // grouped argmax: 4 groups of 8, scalar regs; strict '>' ascending
        // preserves first-occurrence exactly (incl. all-invalid -> 0)
        float m0 = -1.f, m1 = -1.f, m2 = -1.f, m3 = -1.f;
        int i0 = 0, i1 = 8, i2 = 16, i3 = 24;
#pragma unroll
        for (int g = 0; g < NG; ++g) {
            const float4 q = gtb4_s[g];              // wave-uniform broadcast
            const float xx1 = fmaxf(r0, q.x), yy1 = fmaxf(r1, q.y);
            const float xx2 = fminf(r2, q.z), yy2 = fminf(r3, q.w);
            const float iw = fmaxf(xx2 - xx1 + 1.f, 0.f);
            const float ih = fmaxf(yy2 - yy1 + 1.f, 0.f);
            const float inter = iw * ih;
            float iou = inter * __builtin_amdgcn_rcpf(ar + ags_s[g] - inter);
            iou = ((vmask >> g) & 1u) ? iou : -1.0f;
            if (g < 8)       { if (iou > m0) { m0 = iou; i0 = g; } }
            else if (g < 16) { if (iou > m1) { m1 = iou; i1 = g; } }
            else if (g < 24) { if (iou > m2) { m2 = iou; i2 = g; } }
            else             { if (iou > m3) { m3 = iou; i3 = g; } }
        }
        float best = m0; int agt = i0;
        if (m1 > best) { best = m1; agt = i1; }
        if (m2 > best) { best = m2; agt = i2; }
        if (m3 > best) { best = m3; agt = i3; }

        bool fg = best >= 0.5f;
        const int agt_orig = agt;
        const int f = fixmap[k * BLK + tid];
        if (f >= 0) {
            if (f & 0x40000000) fg = true;
            const int code = f & 63;
            agt = (code == 32) ? agt_orig : code;
        }
        if (!live) fg = false; // tail lanes contribute nothing
        const bool bgm = live && (!fg) && (best < 0.5f) && (best >= 0.0f);
        const float active = (fg || bgm) ? 1.f : 0.f;
        const int lbl = fg ? lbl_s[agt] : 0;

        const float mx = fmaxf(fmaxf(cv0.x, cv0.y), fmaxf(cv0.z, cv0.w));
        const float se = __expf(cv0.x - mx) + __expf(cv0.y - mx) +
                         __expf(cv0.z - mx) + __expf(cv0.w - mx);
        const float lse = mx + __logf(se);
        const float csel = (lbl == 0) ? cv0.x : (lbl == 1) ? cv0.y
                         : (lbl == 2) ? cv0.z : cv0.w;
        sum_ce += (lse - csel) * active;
        sum_act += active;

        if (fg) { // rare: exec-masked gathers, issued only when needed
            sum_fg += 1.f;
            const float w = r2 - r0 + 1.f, h = r3 - r1 + 1.f;
            const float rw = __builtin_amdgcn_rcpf(w);
            const float rh = __builtin_amdgcn_rcpf(h);
            const float cx = r0 + 0.5f * w, cy = r1 + 0.5f * h;
            const float4 Gq = gtb4_s[agt];
            const float gw = Gq.z - Gq.x + 1.f, gh = Gq.w - Gq.y + 1.f;
            const float gcx = Gq.x + 0.5f * gw, gcy = Gq.y + 0.5f * gh;
            float t2[4];
            t2[0] = (gcx - cx) * rw;
            t2[1] = (gcy - cy) * rh;
            t2[2] = __logf(gw * rw);
            t2[3] = __logf(gh * rh);
            const float4 b2 = *(const float4*)(bbox_2d + (bbase + a) * 4);
            const float b2v[4] = {b2.x, b2.y, b2.z, b2.w};
            float l2 = 0.f;
            for (int j = 0; j < 4; ++j)
                l2 += smooth_l1(b2v[j] - (t2[j] - mean_s[j]) * rstd_s[j]);
            sum_2d += l2;
            const float* q3p = &gt3_s[agt * 7];
            const float* b3 = bbox_3d + (bbase + a) * 7;
            float t3[7];
            t3[0] = (q3p[0] - cx) * rw;
            t3[1] = (q3p[1] - cy) * rh;
            t3[2] = q3p[2] - anch9[t * 9 + 4];
            t3[3] = __logf(q3p[3] * __builtin_amdgcn_rcpf(anch9[t * 9 + 5]));
            t3[4] = __logf(q3p[4] * __builtin_amdgcn_rcpf(anch9[t * 9 + 6]));
            t3[5] = __logf(q3p[5] * __builtin_amdgcn_rcpf(anch9[t * 9 + 7]));
            t3[6] = q3p[6] - anch9[t * 9 + 8];
            float l3 = 0.f;
            for (int j = 0; j < 7; ++j)
                l3 += smooth_l1(b3[j] - (t3[j] - mean_s[4 + j]) * rstd_s[4 + j]);
            sum_3d += l3;
        }
        cv0 = cv1;
        cv1 = cv2;
        chunk += CB;
    }

    // ---- block reduce -> 5 atomics; last block finishes ----
    float vals[5] = {sum_ce, sum_act, sum_fg, sum_2d, sum_3d};
#pragma unroll
    for (int j = 0; j < 5; ++j) {
        float v = vals[j];
        for (int off = 32; off; off >>= 1) v += __shfl_down(v, off, 64);
        if ((tid & 63) == 0) red[j][tid >> 6] = v;
    }
    __syncthreads();
    if (tid == 0) {
        for (int j = 0; j < 5; ++j) {
            float s = 0.f;
            for (int w = 0; w < BLK / 64; ++w) s += red[j][w];
            atomicAdd(&acc[j], s);
        }
        __threadfence();
        const unsigned old = atomicAdd(done, 1u);
        if (old == G2 - 1) {
            const float a0 = atomicAdd(&acc[0], 0.f);
            const float a1 = atomicAdd(&acc[1], 0.f);
            const float a2 = atomicAdd(&acc[2], 0.f);
            const float a3 = atomicAdd(&acc[3], 0.f);
            const float a4 = atomicAdd(&acc[4], 0.f);
            const float nact = fmaxf(a1, 1.f);
            const float nfg = fmaxf(a2, 1.f);
            out[0] = a0 / nact + a3 / nfg + a4 / nfg;
        }
    }
}

extern "C" void kernel_launch(void* const* d_in, const int* in_sizes, int n_in,
                              void* d_out, int out_size, void* d_ws, size_t ws_size,
                              hipStream_t stream) {
    const float* cls      = (const float*)d_in[0];
    const float* bbox_2d  = (const float*)d_in[1];
    const float* bbox_3d  = (const float*)d_in[2];
    const float* gt_boxes = (const float*)d_in[3];
    const float* gt_3d    = (const float*)d_in[4];
    const int*   gt_labels= (const int*)d_in[5];
    const int*   gt_valid = (const int*)d_in[6];
    const float* anchors  = (const float*)d_in[7];
    const float* means    = (const float*)d_in[8];
    const float* stds     = (const float*)d_in[9];

    unsigned long long* colpart = (unsigned long long*)d_ws;  // 8 KB @0
    float* acc = (float*)((char*)d_ws + 8192);
    unsigned* done = (unsigned*)((char*)d_ws + 8192 + 32);
    float* out = (float*)d_out;

    k_colpass<<<NB * NG * SLICES, CPB, 0, stream>>>(gt_boxes, gt_valid, anchors,
                                                    colpart, acc, done);
    k_main<<<G2, BLK, 0, stream>>>(cls, bbox_2d, bbox_3d, gt_boxes, gt_3d,
                                   gt_labels, gt_valid, anchors, means, stds,
                                   colpart, acc, done, out);
}